// Round 4
// baseline (123.532 us; speedup 1.0000x reference)
//
#include <hip/hip_runtime.h>

// DensityLoss: out[b,y,x] = loss[b,y,x] * (fg ? 10 : 1) / (H*W) / B
// fg = pixel covered by >= 1 of 64 half-open boxes (x1,y1,x2,y2) per batch.
// B=8, H=W=1024, N=64. pred_densities unused by the math.
//
// R4: single fused launch (R3's 2-kernel split regressed: +1 launch + graph
// dependency edge cost more than the build-kernel it saved). One block per
// row. vs R1: no box-staging LDS / no first barrier (4 KB box table is
// L1/L2-resident; each thread reads its 8 boxes directly), loss float4 load
// issued BEFORE mask work to hide latency, fold via 2x ds_read_b128.
//
// Per thread: 8 box tests -> part[t]; 1 barrier; OR-fold 8 partials;
// 1 float4 load + 1 float4 store. Memory-bound: 64 MB stream.
//
// Numerics: /2^20 and /8 are exact pow2 scalings; (loss*w)*0x1p-23f is
// bit-exact vs reference (absmax=0 in R1-R3).

#define NBOX 64

__global__ __launch_bounds__(256) void density_loss_kernel(
    const float* __restrict__ loss,
    const int4*  __restrict__ bboxes,
    float*       __restrict__ out)
{
    __shared__ unsigned int part[256];

    const int t   = threadIdx.x;
    const int row = blockIdx.x;          // b*1024 + y  (block-uniform)
    const int b   = row >> 10;
    const int y   = row & 1023;

    // issue the streaming load first so its latency hides under mask work
    const size_t base = (size_t)row << 10;
    const float4 l = reinterpret_cast<const float4*>(loss + base)[t];

    // coverage word (t>>3) vs box group (t&7): 8 box tests per thread,
    // boxes read straight from global (4 KB table, L1/L2-resident)
    {
        const int word = t >> 3;             // 0..31
        const int g    = t & 7;              // 0..7
        const int lo_w = word << 5;
        const int4* __restrict__ box = bboxes + b * NBOX + g * 8;
        unsigned int m = 0u;
        #pragma unroll
        for (int j = 0; j < 8; ++j) {
            const int4 bx = box[j];
            const bool yin = (y >= bx.y) && (y < bx.w);
            const int lo = max(bx.x, lo_w);
            const int hi = min(bx.z, lo_w + 32);
            if (yin && (lo < hi)) {
                const int len = hi - lo;
                const unsigned int bits =
                    (len >= 32) ? 0xFFFFFFFFu : ((1u << len) - 1u);
                m |= bits << (lo - lo_w);
            }
        }
        part[t] = m;
    }
    __syncthreads();

    // OR-fold my word's 8 partials via two b128 LDS reads (32B-aligned;
    // 2-way bank aliasing is free on gfx950)
    const int wbase = t & ~7;
    const uint4 p0 = reinterpret_cast<const uint4*>(part + wbase)[0];
    const uint4 p1 = reinterpret_cast<const uint4*>(part + wbase)[1];
    const unsigned int cov = (p0.x | p0.y) | (p0.z | p0.w)
                           | (p1.x | p1.y) | (p1.z | p1.w);

    const int sh = (t & 7) << 2;         // bit offset of pixel 4t within word
    const float C = 0x1p-23f;            // 1/(H*W)/B, exact

    float4 o;
    o.x = (l.x * (((cov >> (sh + 0)) & 1u) ? 10.0f : 1.0f)) * C;
    o.y = (l.y * (((cov >> (sh + 1)) & 1u) ? 10.0f : 1.0f)) * C;
    o.z = (l.z * (((cov >> (sh + 2)) & 1u) ? 10.0f : 1.0f)) * C;
    o.w = (l.w * (((cov >> (sh + 3)) & 1u) ? 10.0f : 1.0f)) * C;
    reinterpret_cast<float4*>(out + base)[t] = o;
}

extern "C" void kernel_launch(void* const* d_in, const int* in_sizes, int n_in,
                              void* d_out, int out_size, void* d_ws, size_t ws_size,
                              hipStream_t stream) {
    const float* loss   = (const float*)d_in[0];
    // d_in[1] = pred_densities: unused by the reference math
    const int4*  bboxes = (const int4*)d_in[2];
    float*       out    = (float*)d_out;

    const int n_rows = 8 * 1024;  // B * H
    density_loss_kernel<<<dim3(n_rows), dim3(256), 0, stream>>>(loss, bboxes, out);
}

// Round 5
// 108.846 us; speedup vs baseline: 1.1349x; 1.1349x over previous
//
#include <hip/hip_runtime.h>

// DensityLoss: out[b,y,x] = loss[b,y,x] * (fg ? 10 : 1) / (H*W) / B
// fg = pixel covered by >= 1 of 64 half-open boxes (x1,y1,x2,y2) per batch.
// B=8, H=W=1024, N=64. pred_densities unused by the math.
//
// R5: barrier-free, LDS-free, wave-local. Each wave covers 256 pixels
// (8 coverage words). Lane l: computes partial coverage of word (l&7)
// against box group (l>>3) -> 8 box tests/lane; OR-fold across groups via
// 3x __shfl_xor (stride 8/16/32, in-register); 1x __shfl redistributes
// word (l>>3) to lane l. Waves fully independent: nothing blocks latency
// hiding. Per lane: 1 float4 stream load (issued first), 8 L1-hot box
// loads, ~70 VALU, 4 cross-lane, 1 float4 store. Memory-bound 64 MB.
//
// Numerics: /2^20 and /8 are exact pow2 scalings; (loss*w)*0x1p-23f is
// bit-exact vs reference (absmax=0 in R1-R4).

#define NBOX 64

__global__ __launch_bounds__(256) void density_loss_kernel(
    const float* __restrict__ loss,
    const int4*  __restrict__ bboxes,
    float*       __restrict__ out)
{
    const int t   = threadIdx.x;
    const int row = blockIdx.x;          // b*1024 + y  (block-uniform)
    const int b   = row >> 10;
    const int y   = row & 1023;

    // stream load first: its latency hides under the mask work
    const size_t base = (size_t)row << 10;
    const float4 l = reinterpret_cast<const float4*>(loss + base)[t];

    const int lane     = t & 63;
    const int waveBase = (t & ~63) << 2;     // first pixel of wave's 256-px span
    const int w        = lane & 7;           // coverage word within span
    const int g        = lane >> 3;          // box group
    const int lo_w     = waveBase + (w << 5);

    // 8 box tests: partial coverage of word w vs boxes g*8..g*8+7
    const int4* __restrict__ box = bboxes + b * NBOX + g * 8;
    unsigned int m = 0u;
    #pragma unroll
    for (int j = 0; j < 8; ++j) {
        const int4 bx = box[j];              // L1-hot (4 KB table)
        const bool yin = (y >= bx.y) && (y < bx.w);
        const int lo = max(bx.x, lo_w);
        const int hi = min(bx.z, lo_w + 32);
        if (yin && (lo < hi)) {
            const int len = hi - lo;
            const unsigned int bits =
                (len >= 32) ? 0xFFFFFFFFu : ((1u << len) - 1u);
            m |= bits << (lo - lo_w);
        }
    }

    // OR-fold across the 8 box groups (lanes stride-8 apart share a word)
    m |= __shfl_xor(m, 8,  64);
    m |= __shfl_xor(m, 16, 64);
    m |= __shfl_xor(m, 32, 64);
    // lane l's 4 pixels live in word (l>>3); lanes 0..7 hold words 0..7
    const unsigned int cov = __shfl(m, lane >> 3, 64);

    const int sh = (lane & 7) << 2;          // bit offset of pixel 4l in word
    const float C = 0x1p-23f;                // 1/(H*W)/B, exact

    float4 o;
    o.x = (l.x * (((cov >> (sh + 0)) & 1u) ? 10.0f : 1.0f)) * C;
    o.y = (l.y * (((cov >> (sh + 1)) & 1u) ? 10.0f : 1.0f)) * C;
    o.z = (l.z * (((cov >> (sh + 2)) & 1u) ? 10.0f : 1.0f)) * C;
    o.w = (l.w * (((cov >> (sh + 3)) & 1u) ? 10.0f : 1.0f)) * C;
    reinterpret_cast<float4*>(out + base)[t] = o;
}

extern "C" void kernel_launch(void* const* d_in, const int* in_sizes, int n_in,
                              void* d_out, int out_size, void* d_ws, size_t ws_size,
                              hipStream_t stream) {
    const float* loss   = (const float*)d_in[0];
    // d_in[1] = pred_densities: unused by the reference math
    const int4*  bboxes = (const int4*)d_in[2];
    float*       out    = (float*)d_out;

    const int n_rows = 8 * 1024;  // B * H
    density_loss_kernel<<<dim3(n_rows), dim3(256), 0, stream>>>(loss, bboxes, out);
}